// Round 7
// baseline (671.776 us; speedup 1.0000x reference)
//
#include <hip/hip_runtime.h>

// ---------- bf16 helpers (raw ushort bit ops, RNE store) ----------
__device__ __forceinline__ float bf2f(unsigned short u) {
  union { unsigned int i; float f; } c; c.i = ((unsigned int)u) << 16; return c.f;
}
__device__ __forceinline__ unsigned short f2bf(float f) {
  union { float f; unsigned int i; } c; c.f = f;
  unsigned int x = c.i;
  return (unsigned short)((x + 0x7fffu + ((x >> 16) & 1u)) >> 16);
}
__device__ __forceinline__ float lo16(unsigned int w) { return bf2f((unsigned short)(w & 0xffffu)); }
__device__ __forceinline__ float hi16(unsigned int w) { return bf2f((unsigned short)(w >> 16)); }

#define DD 128
#define HH 64
#define CC 40

// ---------- dtype detect ----------
__global__ void detect(const unsigned int* e32, const unsigned int* x32, int* flags) {
  __shared__ unsigned int redOr[256];
  __shared__ int redCnt[256];
  int tid = threadIdx.x;
  unsigned int v = 0;
  for (int i = tid; i < 4096; i += 256) v |= e32[2 * i + 1];
  int cnt = 0;
  for (int i = tid; i < 4096; i += 256) {
    unsigned int w = x32[i];
    unsigned int expo = (w >> 7) & 0xffu;
    unsigned short lo = (unsigned short)(w & 0xffffu);
    if (lo == 0 || (expo >= 100u && expo <= 133u)) cnt++;
  }
  redOr[tid] = v; redCnt[tid] = cnt; __syncthreads();
  for (int s = 128; s > 0; s >>= 1) {
    if (tid < s) { redOr[tid] |= redOr[tid + s]; redCnt[tid] += redCnt[tid + s]; }
    __syncthreads();
  }
  if (tid == 0) {
    flags[0] = (redOr[0] == 0u) ? 1 : 0;
    flags[1] = (redCnt[0] < 2048) ? 1 : 0;
  }
}

__global__ void count_deg(const int* e32, int E, int N, const int* flags, int* deg) {
  int i = blockIdx.x * blockDim.x + threadIdx.x;
  if (i >= E) return;
  int d = flags[0] ? e32[2 * (E + i)] : e32[E + i];
  d = min(max(d, 0), N - 1);
  atomicAdd(&deg[d], 1);
}

// ---------- scan phase1 (+ prep_w on the extra block) ----------
// Wp1f[p*64+j]  = {W1l[2p][j], W1l[2p+1][j], W1r[2p][j], W1r[2p+1][j]}  (p<64)
// Wp2f[p*80+cc] = {Wcat[2p][cc], Wcat[2p+1][cc]}  (p<32; cc<40 -> W2l col, cc>=40 -> W2r col cc-40)
__global__ void scan_phase1(const int* deg, int n, int* bsums, int NB,
                            const void* W1l, const void* W1r, const void* b1,
                            const void* W2l, const void* W2r, const void* b2,
                            const int* flags, float4* Wp1f, float2* Wp2f,
                            float* b1f, float* b2f) {
  int tid = threadIdx.x;
  if ((int)blockIdx.x == NB) {                 // prep_w role
    int isf = flags[1];
    auto rd = [&](const void* p, int i) -> float {
      return isf ? ((const float*)p)[i] : bf2f(((const unsigned short*)p)[i]);
    };
    for (int idx = tid; idx < 64 * 64; idx += 256) {
      int p = idx >> 6, j = idx & 63;
      Wp1f[idx] = make_float4(rd(W1l, (2 * p) * HH + j), rd(W1l, (2 * p + 1) * HH + j),
                              rd(W1r, (2 * p) * HH + j), rd(W1r, (2 * p + 1) * HH + j));
    }
    for (int idx = tid; idx < 32 * 80; idx += 256) {
      int p = idx / 80, cc = idx % 80;
      float a, b;
      if (cc < CC) { a = rd(W2l, (2 * p) * CC + cc);        b = rd(W2l, (2 * p + 1) * CC + cc); }
      else         { a = rd(W2r, (2 * p) * CC + cc - CC);   b = rd(W2r, (2 * p + 1) * CC + cc - CC); }
      Wp2f[idx] = make_float2(a, b);
    }
    if (tid < HH) b1f[tid] = rd(b1, tid);
    if (tid < CC) b2f[tid] = rd(b2, tid);
    return;
  }
  __shared__ int red[256];
  int base = blockIdx.x * 1024 + tid * 4;
  int s = 0;
  for (int k = 0; k < 4; k++) { int i = base + k; if (i < n) s += deg[i]; }
  red[tid] = s; __syncthreads();
  for (int st = 128; st > 0; st >>= 1) {
    if (tid < st) red[tid] += red[tid + st];
    __syncthreads();
  }
  if (tid == 0) bsums[blockIdx.x] = red[0];
}

__global__ void scan_phase2(int* bsums, int nb, int* row_ptr, int n) {
  __shared__ int tmp[1024];
  int tid = threadIdx.x;
  int v = (tid < nb) ? bsums[tid] : 0;
  tmp[tid] = v; __syncthreads();
  for (int st = 1; st < 1024; st <<= 1) {
    int t = (tid >= st) ? tmp[tid - st] : 0;
    __syncthreads();
    tmp[tid] += t;
    __syncthreads();
  }
  if (tid < nb) bsums[tid] = tmp[tid] - v;
  if (tid == nb - 1) row_ptr[n] = tmp[tid];
}

__global__ void scan_phase3(const int* deg, int n, const int* boff,
                            int* row_ptr, int* fill, float* invd) {
  __shared__ int red[256];
  int tid = threadIdx.x;
  int base = blockIdx.x * 1024 + tid * 4;
  int d[4]; int s = 0;
  for (int k = 0; k < 4; k++) { int i = base + k; d[k] = (i < n) ? deg[i] : 0; s += d[k]; }
  red[tid] = s; __syncthreads();
  for (int st = 1; st < 256; st <<= 1) {
    int t = (tid >= st) ? red[tid - st] : 0;
    __syncthreads();
    red[tid] += t;
    __syncthreads();
  }
  int run = boff[blockIdx.x] + red[tid] - s;
  for (int k = 0; k < 4; k++) {
    int i = base + k;
    if (i < n) {
      row_ptr[i] = run; fill[i] = run;
      invd[i] = 1.0f / (float)max(d[k], 1);
      run += d[k];
    }
  }
}

// ---------- hybrid: fill_csr (scatter-bound) ∥ transform1 (VALU-bound) ----------
__global__ __launch_bounds__(256) void fill_or_t1(
    const int* e32, int E, int N, const int* flags, int* fill, int* col,
    const void* xraw, const float4* Wp1f, const float* b1f,
    unsigned short* t1, unsigned short* s1, int T1B, int FB) {
  __shared__ float vx[32 * DD];            // 16 KB (only used by transform role)
  int b = blockIdx.x;
  int t = b / 3, r3 = b % 3;
  bool role_t = (r3 == 0) && (t < T1B);

  if (!role_t) {                               // ---- fill_csr role ----
    int ntb = min((b + 2) / 3, T1B);           // transform blocks before b
    int fid = b - ntb;
    if (fid >= FB) return;
    int i = fid * 256 + threadIdx.x;
    if (i >= E) return;
    int s, d;
    if (flags[0]) { s = e32[2 * i]; d = e32[2 * (E + i)]; }
    else          { s = e32[i];     d = e32[E + i]; }
    s = min(max(s, 0), N - 1);
    d = min(max(d, 0), N - 1);
    int p = atomicAdd(&fill[d], 1);
    col[p] = s;
    return;
  }

  // ---- transform1 role ----
  int wave = threadIdx.x >> 6, lane = threadIdx.x & 63;
  int nodeBase = t * 32 + wave * 8;
  float* myv = &vx[wave * 8 * DD];

  if (flags[1]) {                                        // fp32 input
    const float2* x2 = (const float2*)xraw;
    for (int k = 0; k < 8; k++) {
      int n = nodeBase + k;
      if (n < N) *(float2*)&myv[k * DD + 2 * lane] = x2[(size_t)n * 64 + lane];
    }
  } else {                                               // bf16 input
    const unsigned int* x32 = (const unsigned int*)xraw;
    for (int k = 0; k < 8; k++) {
      int n = nodeBase + k;
      if (n < N) {
        unsigned int w = x32[(size_t)n * 64 + lane];
        *(float2*)&myv[k * DD + 2 * lane] = make_float2(lo16(w), hi16(w));
      }
    }
  }
  __syncthreads();

  float acct[8] = {0, 0, 0, 0, 0, 0, 0, 0};
  float accs[8] = {0, 0, 0, 0, 0, 0, 0, 0};
  const float2* v2 = (const float2*)myv;
  int j = lane;
  for (int p = 0; p < 64; p++) {
    float4 w = Wp1f[p * 64 + j];
#pragma unroll
    for (int k = 0; k < 8; k++) {
      float2 vv = v2[k * 64 + p];
      acct[k] += vv.x * w.x + vv.y * w.y;
      accs[k] += vv.x * w.z + vv.y * w.w;
    }
  }
  float bb = b1f[j];
  for (int k = 0; k < 8; k++) {
    int n = nodeBase + k;
    if (n < N) {
      t1[n * HH + j] = f2bf(acct[k]);
      s1[n * HH + j] = f2bf(accs[k] + bb);
    }
  }
}

// ---------- vectorized CSR mean-gather (128B rows) ----------
__device__ __forceinline__ void gather_rows(const uint4* t8, const int* col,
                                            int start, int end, int r, int c,
                                            float acc[8]) {
  for (int base = start; base < end; base += 16) {
    int i0 = base + r, i1 = base + 8 + r;
    uint4 v0 = make_uint4(0, 0, 0, 0), v1 = make_uint4(0, 0, 0, 0);
    bool g0 = (i0 < end), g1 = (i1 < end);
    int nb0 = g0 ? col[i0] : 0;
    int nb1 = g1 ? col[i1] : 0;
    if (g0) v0 = t8[nb0 * 8 + c];
    if (g1) v1 = t8[nb1 * 8 + c];
    acc[0] += lo16(v0.x) + lo16(v1.x);
    acc[1] += hi16(v0.x) + hi16(v1.x);
    acc[2] += lo16(v0.y) + lo16(v1.y);
    acc[3] += hi16(v0.y) + hi16(v1.y);
    acc[4] += lo16(v0.z) + lo16(v1.z);
    acc[5] += hi16(v0.z) + hi16(v1.z);
    acc[6] += lo16(v0.w) + lo16(v1.w);
    acc[7] += hi16(v0.w) + hi16(v1.w);
  }
#pragma unroll
  for (int m = 8; m <= 32; m <<= 1)
#pragma unroll
    for (int i = 0; i < 8; i++) acc[i] += __shfl_xor(acc[i], m, 64);
}

// ---------- agg1_uv (fused): h = relu(mean(t1[nbrs]) + s1) [LDS only];
//            uv[n][cc] = (h @ Wcat)[cc] (+b2 for cc>=40)  [global, bf16] ----------
// One wave per node. h row round-trips through 1KB wave-private LDS; each lane
// owns output col cc=lane (and cc=lane+64 for lane<16). Scalar accumulators only.
__global__ __launch_bounds__(256, 4) void agg1_uv(
    const unsigned short* t1, const unsigned short* s1,
    const int* row_ptr, const float* invd, const int* col,
    const float2* Wp2f, const float* b2f, unsigned short* uv, int N) {
  __shared__ float hrow[4][HH];                // 1 KB: 4 waves x 64 floats
  int wave = threadIdx.x >> 6, lane = threadIdx.x & 63;
  int r = lane >> 3, c = lane & 7;
  int n = blockIdx.x * 4 + wave;
  bool valid = (n < N);
  int start = valid ? row_ptr[n] : 0;
  int end   = valid ? row_ptr[n + 1] : 0;

  float acc[8] = {0, 0, 0, 0, 0, 0, 0, 0};
  gather_rows((const uint4*)t1, col, start, end, r, c, acc);

  if (valid && r == 0) {                       // lanes 0..7 hold feats c*8..c*8+7
    float id = invd[n];
    uint4 sv = ((const uint4*)s1)[n * 8 + c];
    float s[8] = {lo16(sv.x), hi16(sv.x), lo16(sv.y), hi16(sv.y),
                  lo16(sv.z), hi16(sv.z), lo16(sv.w), hi16(sv.w)};
#pragma unroll
    for (int i = 0; i < 8; i++)
      hrow[wave][c * 8 + i] = fmaxf(acc[i] * id + s[i], 0.f);
  }
  __syncthreads();                             // uniform: no early returns above

  // matvec: 80 Wcat columns over 64 h features; lane -> col lane (+64 if lane<16)
  const float2* hv = (const float2*)hrow[wave];
  float a0 = 0.f, a1 = 0.f;
  for (int p = 0; p < 32; p++) {
    float2 hh = hv[p];                         // broadcast LDS read
    float2 w0 = Wp2f[p * 80 + lane];
    a0 += hh.x * w0.x + hh.y * w0.y;
    if (lane < 16) {
      float2 w1 = Wp2f[p * 80 + 64 + lane];
      a1 += hh.x * w1.x + hh.y * w1.y;
    }
  }
  if (valid) {
    float bb0 = (lane >= CC) ? b2f[lane - CC] : 0.f;
    uv[(size_t)n * 80 + lane] = f2bf(a0 + bb0);
    if (lane < 16)                             // cc = 64+lane >= 40 always
      uv[(size_t)n * 80 + 64 + lane] = f2bf(a1 + b2f[24 + lane]);
  }
}

// ---------- layer2n: out = log_softmax(mean(uv[nbrs][0:40]) + uv[n][40:80]) ----------
// one wave per node; u part = 40 bf16 = 80B = 5 uint4 chunks of the 160B row (c<5 active).
__global__ __launch_bounds__(256) void layer2n(const unsigned short* uv,
                                               const int* row_ptr, const float* invd,
                                               const int* col, float* out, int N) {
  int wave = threadIdx.x >> 6, lane = threadIdx.x & 63;
  int r = lane >> 3, c = lane & 7;
  int n = blockIdx.x * 4 + wave;
  if (n >= N) return;
  int start = row_ptr[n], end = row_ptr[n + 1];
  const uint4* u4 = (const uint4*)uv;          // row pitch = 10 uint4
  bool cok = (c < 5);

  float acc[8] = {0, 0, 0, 0, 0, 0, 0, 0};
  for (int base = start; base < end; base += 16) {
    int i0 = base + r, i1 = base + 8 + r;
    uint4 v0 = make_uint4(0, 0, 0, 0), v1 = make_uint4(0, 0, 0, 0);
    bool g0 = (i0 < end), g1 = (i1 < end);
    int nb0 = g0 ? col[i0] : 0;
    int nb1 = g1 ? col[i1] : 0;
    if (g0 && cok) v0 = u4[nb0 * 10 + c];
    if (g1 && cok) v1 = u4[nb1 * 10 + c];
    acc[0] += lo16(v0.x) + lo16(v1.x);
    acc[1] += hi16(v0.x) + hi16(v1.x);
    acc[2] += lo16(v0.y) + lo16(v1.y);
    acc[3] += hi16(v0.y) + hi16(v1.y);
    acc[4] += lo16(v0.z) + lo16(v1.z);
    acc[5] += hi16(v0.z) + hi16(v1.z);
    acc[6] += lo16(v0.w) + lo16(v1.w);
    acc[7] += hi16(v0.w) + hi16(v1.w);
  }
#pragma unroll
  for (int m = 8; m <= 32; m <<= 1)
#pragma unroll
    for (int i = 0; i < 8; i++) acc[i] += __shfl_xor(acc[i], m, 64);

  float id = invd[n];
  float lg[8];
  float mx = -INFINITY;
  if (cok) {
    uint4 sv = u4[n * 10 + 5 + c];             // v part: bytes 80..159 of row n
    float s[8] = {lo16(sv.x), hi16(sv.x), lo16(sv.y), hi16(sv.y),
                  lo16(sv.z), hi16(sv.z), lo16(sv.w), hi16(sv.w)};
#pragma unroll
    for (int i = 0; i < 8; i++) {
      lg[i] = acc[i] * id + s[i];
      mx = fmaxf(mx, lg[i]);
    }
  }
#pragma unroll
  for (int m = 1; m <= 4; m <<= 1) mx = fmaxf(mx, __shfl_xor(mx, m, 64));
  float ssum = 0.f;
  if (cok) {
#pragma unroll
    for (int i = 0; i < 8; i++) ssum += __expf(lg[i] - mx);
  }
#pragma unroll
  for (int m = 1; m <= 4; m <<= 1) ssum += __shfl_xor(ssum, m, 64);
  float ls = mx + __logf(ssum);

  if (r == 0 && cok) {
    float4 o0 = make_float4(lg[0] - ls, lg[1] - ls, lg[2] - ls, lg[3] - ls);
    float4 o1 = make_float4(lg[4] - ls, lg[5] - ls, lg[6] - ls, lg[7] - ls);
    float* dst = out + (size_t)n * CC + c * 8;
    *(float4*)dst = o0;
    *(float4*)(dst + 4) = o1;
  }
}

extern "C" void kernel_launch(void* const* d_in, const int* in_sizes, int n_in,
                              void* d_out, int out_size, void* d_ws, size_t ws_size,
                              hipStream_t stream) {
  const void* x   = d_in[0];
  const int*  e   = (const int*)d_in[1];
  const void* W1l = d_in[2];
  const void* W1r = d_in[3];
  const void* b1  = d_in[4];
  const void* W2l = d_in[5];
  const void* W2r = d_in[6];
  const void* b2  = d_in[7];
  float* out = (float*)d_out;

  const int N = in_sizes[0] / DD;       // 100000
  const int E = in_sizes[1] / 2;        // 1600000
  const int NB = (N + 1023) / 1024;     // scan blocks (98)
  const int T1B = (N + 31) / 32;        // transform1 blocks (3125)
  const int FB  = (E + 255) / 256;      // fill blocks (6250)
  int hybrid_grid = 3 * T1B;
  if (hybrid_grid < T1B + FB) hybrid_grid = T1B + FB;

  char* w = (char*)d_ws;
  size_t off = 0;
  auto carve = [&](size_t bytes) -> void* {
    void* p = (void*)(w + off);
    off += (bytes + 255) & ~(size_t)255;
    return p;
  };
  int* col     = (int*)carve((size_t)E * 4);
  int* deg     = (int*)carve((size_t)N * 4);
  int* row_ptr = (int*)carve((size_t)(N + 1) * 4);
  int* fill    = (int*)carve((size_t)N * 4);
  float* invd  = (float*)carve((size_t)N * 4);
  int* bsums   = (int*)carve((size_t)(NB + 1) * 4);
  int* flags   = (int*)carve(8);
  unsigned short* t1  = (unsigned short*)carve((size_t)N * HH * 2);
  unsigned short* s1  = (unsigned short*)carve((size_t)N * HH * 2);
  unsigned short* uv  = (unsigned short*)carve((size_t)N * 80 * 2);
  float4* Wp1f = (float4*)carve(64 * 64 * sizeof(float4));
  float2* Wp2f = (float2*)carve(32 * 80 * sizeof(float2));
  float* b1f   = (float*)carve(HH * sizeof(float));
  float* b2f   = (float*)carve(CC * sizeof(float));
  (void)ws_size; (void)n_in; (void)out_size;

  hipMemsetAsync(deg, 0, (size_t)N * 4, stream);
  detect<<<1, 256, 0, stream>>>((const unsigned int*)e, (const unsigned int*)x, flags);
  count_deg<<<FB, 256, 0, stream>>>(e, E, N, flags, deg);
  scan_phase1<<<NB + 1, 256, 0, stream>>>(deg, N, bsums, NB,
                                          W1l, W1r, b1, W2l, W2r, b2,
                                          flags, Wp1f, Wp2f, b1f, b2f);
  scan_phase2<<<1, 1024, 0, stream>>>(bsums, NB, row_ptr, N);
  scan_phase3<<<NB, 256, 0, stream>>>(deg, N, bsums, row_ptr, fill, invd);
  fill_or_t1<<<hybrid_grid, 256, 0, stream>>>(e, E, N, flags, fill, col,
                                              x, Wp1f, b1f, t1, s1, T1B, FB);
  agg1_uv<<<(N + 3) / 4, 256, 0, stream>>>(t1, s1, row_ptr, invd, col,
                                           Wp2f, b2f, uv, N);
  layer2n<<<(N + 3) / 4, 256, 0, stream>>>(uv, row_ptr, invd, col, out, N);
}

// Round 8
// 446.806 us; speedup vs baseline: 1.5035x; 1.5035x over previous
//
#include <hip/hip_runtime.h>

// ---------- bf16 helpers (raw ushort bit ops, RNE store) ----------
__device__ __forceinline__ float bf2f(unsigned short u) {
  union { unsigned int i; float f; } c; c.i = ((unsigned int)u) << 16; return c.f;
}
__device__ __forceinline__ unsigned short f2bf(float f) {
  union { float f; unsigned int i; } c; c.f = f;
  unsigned int x = c.i;
  return (unsigned short)((x + 0x7fffu + ((x >> 16) & 1u)) >> 16);
}
__device__ __forceinline__ float lo16(unsigned int w) { return bf2f((unsigned short)(w & 0xffffu)); }
__device__ __forceinline__ float hi16(unsigned int w) { return bf2f((unsigned short)(w >> 16)); }

#define DD 128
#define HH 64
#define CC 40

// ---------- dtype detect ----------
__global__ void detect(const unsigned int* e32, const unsigned int* x32, int* flags) {
  __shared__ unsigned int redOr[256];
  __shared__ int redCnt[256];
  int tid = threadIdx.x;
  unsigned int v = 0;
  for (int i = tid; i < 4096; i += 256) v |= e32[2 * i + 1];
  int cnt = 0;
  for (int i = tid; i < 4096; i += 256) {
    unsigned int w = x32[i];
    unsigned int expo = (w >> 7) & 0xffu;
    unsigned short lo = (unsigned short)(w & 0xffffu);
    if (lo == 0 || (expo >= 100u && expo <= 133u)) cnt++;
  }
  redOr[tid] = v; redCnt[tid] = cnt; __syncthreads();
  for (int s = 128; s > 0; s >>= 1) {
    if (tid < s) { redOr[tid] |= redOr[tid + s]; redCnt[tid] += redCnt[tid + s]; }
    __syncthreads();
  }
  if (tid == 0) {
    flags[0] = (redOr[0] == 0u) ? 1 : 0;
    flags[1] = (redCnt[0] < 2048) ? 1 : 0;
  }
}

__global__ void count_deg(const int* e32, int E, int N, const int* flags, int* deg) {
  int i = blockIdx.x * blockDim.x + threadIdx.x;
  if (i >= E) return;
  int d = flags[0] ? e32[2 * (E + i)] : e32[E + i];
  d = min(max(d, 0), N - 1);
  atomicAdd(&deg[d], 1);
}

// ---------- scan phase1 (+ prep_w on the extra block) ----------
// Wp1f[p*64+j] = {W1l[2p][j], W1l[2p+1][j], W1r[2p][j], W1r[2p+1][j]}  (p<64)
// Wc2f[p*64+j] = {Wcat[2p][j], Wcat[2p+1][j]} for j<40 else {0,0}      (p<64)
//   Wcat[k][j] = (k<64) ? W2l[k][j] : W2r[k-64][j]   (aggh feats first, self feats second)
__global__ void scan_phase1(const int* deg, int n, int* bsums, int NB,
                            const void* W1l, const void* W1r, const void* b1,
                            const void* W2l, const void* W2r, const void* b2,
                            const int* flags, float4* Wp1f, float2* Wc2f,
                            float* b1f, float* b2f) {
  int tid = threadIdx.x;
  if ((int)blockIdx.x == NB) {                 // prep_w role
    int isf = flags[1];
    auto rd = [&](const void* p, int i) -> float {
      return isf ? ((const float*)p)[i] : bf2f(((const unsigned short*)p)[i]);
    };
    auto wcat = [&](int k, int j) -> float {
      return (k < HH) ? rd(W2l, k * CC + j) : rd(W2r, (k - HH) * CC + j);
    };
    for (int idx = tid; idx < 64 * 64; idx += 256) {
      int p = idx >> 6, j = idx & 63;
      Wp1f[idx] = make_float4(rd(W1l, (2 * p) * HH + j), rd(W1l, (2 * p + 1) * HH + j),
                              rd(W1r, (2 * p) * HH + j), rd(W1r, (2 * p + 1) * HH + j));
      Wc2f[idx] = (j < CC) ? make_float2(wcat(2 * p, j), wcat(2 * p + 1, j))
                           : make_float2(0.f, 0.f);
    }
    if (tid < HH) b1f[tid] = rd(b1, tid);
    if (tid < CC) b2f[tid] = rd(b2, tid);
    return;
  }
  __shared__ int red[256];
  int base = blockIdx.x * 1024 + tid * 4;
  int s = 0;
  for (int k = 0; k < 4; k++) { int i = base + k; if (i < n) s += deg[i]; }
  red[tid] = s; __syncthreads();
  for (int st = 128; st > 0; st >>= 1) {
    if (tid < st) red[tid] += red[tid + st];
    __syncthreads();
  }
  if (tid == 0) bsums[blockIdx.x] = red[0];
}

__global__ void scan_phase2(int* bsums, int nb, int* row_ptr, int n) {
  __shared__ int tmp[1024];
  int tid = threadIdx.x;
  int v = (tid < nb) ? bsums[tid] : 0;
  tmp[tid] = v; __syncthreads();
  for (int st = 1; st < 1024; st <<= 1) {
    int t = (tid >= st) ? tmp[tid - st] : 0;
    __syncthreads();
    tmp[tid] += t;
    __syncthreads();
  }
  if (tid < nb) bsums[tid] = tmp[tid] - v;
  if (tid == nb - 1) row_ptr[n] = tmp[tid];
}

__global__ void scan_phase3(const int* deg, int n, const int* boff,
                            int* row_ptr, int* fill, float* invd) {
  __shared__ int red[256];
  int tid = threadIdx.x;
  int base = blockIdx.x * 1024 + tid * 4;
  int d[4]; int s = 0;
  for (int k = 0; k < 4; k++) { int i = base + k; d[k] = (i < n) ? deg[i] : 0; s += d[k]; }
  red[tid] = s; __syncthreads();
  for (int st = 1; st < 256; st <<= 1) {
    int t = (tid >= st) ? red[tid - st] : 0;
    __syncthreads();
    red[tid] += t;
    __syncthreads();
  }
  int run = boff[blockIdx.x] + red[tid] - s;
  for (int k = 0; k < 4; k++) {
    int i = base + k;
    if (i < n) {
      row_ptr[i] = run; fill[i] = run;
      invd[i] = 1.0f / (float)max(d[k], 1);
      run += d[k];
    }
  }
}

// ---------- hybrid: fill_csr (scatter-bound) ∥ transform1 (VALU-bound) ----------
__global__ __launch_bounds__(256) void fill_or_t1(
    const int* e32, int E, int N, const int* flags, int* fill, int* col,
    const void* xraw, const float4* Wp1f, const float* b1f,
    unsigned short* t1, unsigned short* s1, int T1B, int FB) {
  __shared__ float vx[32 * DD];            // 16 KB (only used by transform role)
  int b = blockIdx.x;
  int t = b / 3, r3 = b % 3;
  bool role_t = (r3 == 0) && (t < T1B);

  if (!role_t) {                               // ---- fill_csr role ----
    int ntb = min((b + 2) / 3, T1B);
    int fid = b - ntb;
    if (fid >= FB) return;
    int i = fid * 256 + threadIdx.x;
    if (i >= E) return;
    int s, d;
    if (flags[0]) { s = e32[2 * i]; d = e32[2 * (E + i)]; }
    else          { s = e32[i];     d = e32[E + i]; }
    s = min(max(s, 0), N - 1);
    d = min(max(d, 0), N - 1);
    int p = atomicAdd(&fill[d], 1);
    col[p] = s;
    return;
  }

  // ---- transform1 role ----
  int wave = threadIdx.x >> 6, lane = threadIdx.x & 63;
  int nodeBase = t * 32 + wave * 8;
  float* myv = &vx[wave * 8 * DD];

  if (flags[1]) {                                        // fp32 input
    const float2* x2 = (const float2*)xraw;
    for (int k = 0; k < 8; k++) {
      int n = nodeBase + k;
      if (n < N) *(float2*)&myv[k * DD + 2 * lane] = x2[(size_t)n * 64 + lane];
    }
  } else {                                               // bf16 input
    const unsigned int* x32 = (const unsigned int*)xraw;
    for (int k = 0; k < 8; k++) {
      int n = nodeBase + k;
      if (n < N) {
        unsigned int w = x32[(size_t)n * 64 + lane];
        *(float2*)&myv[k * DD + 2 * lane] = make_float2(lo16(w), hi16(w));
      }
    }
  }
  __syncthreads();

  float acct[8] = {0, 0, 0, 0, 0, 0, 0, 0};
  float accs[8] = {0, 0, 0, 0, 0, 0, 0, 0};
  const float2* v2 = (const float2*)myv;
  int j = lane;
  for (int p = 0; p < 64; p++) {
    float4 w = Wp1f[p * 64 + j];
#pragma unroll
    for (int k = 0; k < 8; k++) {
      float2 vv = v2[k * 64 + p];
      acct[k] += vv.x * w.x + vv.y * w.y;
      accs[k] += vv.x * w.z + vv.y * w.w;
    }
  }
  float bb = b1f[j];
  for (int k = 0; k < 8; k++) {
    int n = nodeBase + k;
    if (n < N) {
      t1[n * HH + j] = f2bf(acct[k]);
      s1[n * HH + j] = f2bf(accs[k] + bb);
    }
  }
}

// ---------- vectorized CSR mean-gather (128B rows) ----------
__device__ __forceinline__ void gather_rows(const uint4* t8, const int* col,
                                            int start, int end, int r, int c,
                                            float acc[8]) {
  for (int base = start; base < end; base += 16) {
    int i0 = base + r, i1 = base + 8 + r;
    uint4 v0 = make_uint4(0, 0, 0, 0), v1 = make_uint4(0, 0, 0, 0);
    bool g0 = (i0 < end), g1 = (i1 < end);
    int nb0 = g0 ? col[i0] : 0;
    int nb1 = g1 ? col[i1] : 0;
    if (g0) v0 = t8[nb0 * 8 + c];
    if (g1) v1 = t8[nb1 * 8 + c];
    acc[0] += lo16(v0.x) + lo16(v1.x);
    acc[1] += hi16(v0.x) + hi16(v1.x);
    acc[2] += lo16(v0.y) + lo16(v1.y);
    acc[3] += hi16(v0.y) + hi16(v1.y);
    acc[4] += lo16(v0.z) + lo16(v1.z);
    acc[5] += hi16(v0.z) + hi16(v1.z);
    acc[6] += lo16(v0.w) + lo16(v1.w);
    acc[7] += hi16(v0.w) + hi16(v1.w);
  }
#pragma unroll
  for (int m = 8; m <= 32; m <<= 1)
#pragma unroll
    for (int i = 0; i < 8; i++) acc[i] += __shfl_xor(acc[i], m, 64);
}

// ---------- aggregate1: h = relu(mean(t1[nbrs]) + s1) ----------
__global__ __launch_bounds__(256) void aggregate1(const unsigned short* t1,
                                                  const unsigned short* s1,
                                                  const int* row_ptr, const float* invd,
                                                  const int* col, unsigned short* h, int N) {
  int wave = threadIdx.x >> 6, lane = threadIdx.x & 63;
  int r = lane >> 3, c = lane & 7;
  int n = blockIdx.x * 4 + wave;
  if (n >= N) return;
  int start = row_ptr[n], end = row_ptr[n + 1];
  float acc[8] = {0, 0, 0, 0, 0, 0, 0, 0};
  gather_rows((const uint4*)t1, col, start, end, r, c, acc);

  if (r == 0) {
    float id = invd[n];
    uint4 sv = ((const uint4*)s1)[n * 8 + c];
    float s[8] = {lo16(sv.x), hi16(sv.x), lo16(sv.y), hi16(sv.y),
                  lo16(sv.z), hi16(sv.z), lo16(sv.w), hi16(sv.w)};
    unsigned int o[4];
#pragma unroll
    for (int i = 0; i < 4; i++) {
      float a0 = fmaxf(acc[2 * i] * id + s[2 * i], 0.f);
      float a1 = fmaxf(acc[2 * i + 1] * id + s[2 * i + 1], 0.f);
      o[i] = (unsigned int)f2bf(a0) | ((unsigned int)f2bf(a1) << 16);
    }
    ((uint4*)h)[n * 8 + c] = make_uint4(o[0], o[1], o[2], o[3]);
  }
}

// ---------- agg2: aggh = mean(h[nbrs])  (pure gather, same proven shape) ----------
__global__ __launch_bounds__(256) void agg2(const unsigned short* h,
                                            const int* row_ptr, const float* invd,
                                            const int* col, unsigned short* aggh, int N) {
  int wave = threadIdx.x >> 6, lane = threadIdx.x & 63;
  int r = lane >> 3, c = lane & 7;
  int n = blockIdx.x * 4 + wave;
  if (n >= N) return;
  int start = row_ptr[n], end = row_ptr[n + 1];
  float acc[8] = {0, 0, 0, 0, 0, 0, 0, 0};
  gather_rows((const uint4*)h, col, start, end, r, c, acc);

  if (r == 0) {
    float id = invd[n];
    unsigned int o[4];
#pragma unroll
    for (int i = 0; i < 4; i++) {
      o[i] = (unsigned int)f2bf(acc[2 * i] * id) |
             ((unsigned int)f2bf(acc[2 * i + 1] * id) << 16);
    }
    ((uint4*)aggh)[n * 8 + c] = make_uint4(o[0], o[1], o[2], o[3]);
  }
}

// ---------- final: out = log_softmax([aggh|h] @ Wcat + b2)  (transform1 skeleton) ----------
// 4 waves/block, wave owns 8 nodes; lane j owns output col j (cols 40..63 are zero-padded).
__global__ __launch_bounds__(256) void final_k(const unsigned short* aggh,
                                               const unsigned short* h,
                                               const float2* Wc2f, const float* b2f,
                                               float* out, int N) {
  __shared__ float vx[32 * DD];            // 16 KB: 32 nodes x 128 floats
  int wave = threadIdx.x >> 6, lane = threadIdx.x & 63;
  int nodeBase = blockIdx.x * 32 + wave * 8;
  float* myv = &vx[wave * 8 * DD];
  int row = lane >> 3, chunk = lane & 7;     // 8 rows x 8 chunks (16B each)
  int n0 = nodeBase + row;

  if (n0 < N) {
    uint4 va = ((const uint4*)aggh)[(size_t)n0 * 8 + chunk];
    float* d0 = &myv[row * DD + chunk * 8];
    d0[0] = lo16(va.x); d0[1] = hi16(va.x); d0[2] = lo16(va.y); d0[3] = hi16(va.y);
    d0[4] = lo16(va.z); d0[5] = hi16(va.z); d0[6] = lo16(va.w); d0[7] = hi16(va.w);
    uint4 vh = ((const uint4*)h)[(size_t)n0 * 8 + chunk];
    float* d1 = &myv[row * DD + 64 + chunk * 8];
    d1[0] = lo16(vh.x); d1[1] = hi16(vh.x); d1[2] = lo16(vh.y); d1[3] = hi16(vh.y);
    d1[4] = lo16(vh.z); d1[5] = hi16(vh.z); d1[6] = lo16(vh.w); d1[7] = hi16(vh.w);
  }
  __syncthreads();

  float acc[8] = {0, 0, 0, 0, 0, 0, 0, 0};
  const float2* v2 = (const float2*)myv;
  int j = lane;
  for (int p = 0; p < 64; p++) {
    float2 w = Wc2f[p * 64 + j];
#pragma unroll
    for (int k = 0; k < 8; k++) {
      float2 vv = v2[k * 64 + p];              // broadcast LDS read
      acc[k] += vv.x * w.x + vv.y * w.y;
    }
  }
  float bb = (j < CC) ? b2f[j] : 0.f;
  for (int k = 0; k < 8; k++) {
    int n = nodeBase + k;
    float val = (j < CC) ? acc[k] + bb : -INFINITY;
    float m = val;
    for (int off = 32; off > 0; off >>= 1) m = fmaxf(m, __shfl_xor(m, off, 64));
    float e = (j < CC) ? __expf(val - m) : 0.f;
    float ssum = e;
    for (int off = 32; off > 0; off >>= 1) ssum += __shfl_xor(ssum, off, 64);
    if (j < CC && n < N) {
      out[(size_t)n * CC + j] = val - m - __logf(ssum);
    }
  }
}

extern "C" void kernel_launch(void* const* d_in, const int* in_sizes, int n_in,
                              void* d_out, int out_size, void* d_ws, size_t ws_size,
                              hipStream_t stream) {
  const void* x   = d_in[0];
  const int*  e   = (const int*)d_in[1];
  const void* W1l = d_in[2];
  const void* W1r = d_in[3];
  const void* b1  = d_in[4];
  const void* W2l = d_in[5];
  const void* W2r = d_in[6];
  const void* b2  = d_in[7];
  float* out = (float*)d_out;

  const int N = in_sizes[0] / DD;       // 100000
  const int E = in_sizes[1] / 2;        // 1600000
  const int NB = (N + 1023) / 1024;     // scan blocks (98)
  const int T1B = (N + 31) / 32;        // transform1 blocks (3125)
  const int FB  = (E + 255) / 256;      // fill blocks (6250)
  int hybrid_grid = 3 * T1B;
  if (hybrid_grid < T1B + FB) hybrid_grid = T1B + FB;

  char* w = (char*)d_ws;
  size_t off = 0;
  auto carve = [&](size_t bytes) -> void* {
    void* p = (void*)(w + off);
    off += (bytes + 255) & ~(size_t)255;
    return p;
  };
  int* col     = (int*)carve((size_t)E * 4);
  int* deg     = (int*)carve((size_t)N * 4);
  int* row_ptr = (int*)carve((size_t)(N + 1) * 4);
  int* fill    = (int*)carve((size_t)N * 4);
  float* invd  = (float*)carve((size_t)N * 4);
  int* bsums   = (int*)carve((size_t)(NB + 1) * 4);
  int* flags   = (int*)carve(8);
  unsigned short* t1   = (unsigned short*)carve((size_t)N * HH * 2);
  unsigned short* s1   = (unsigned short*)carve((size_t)N * HH * 2);
  unsigned short* h    = (unsigned short*)carve((size_t)N * HH * 2);
  unsigned short* aggh = (unsigned short*)carve((size_t)N * HH * 2);
  float4* Wp1f = (float4*)carve(64 * 64 * sizeof(float4));
  float2* Wc2f = (float2*)carve(64 * 64 * sizeof(float2));
  float* b1f   = (float*)carve(HH * sizeof(float));
  float* b2f   = (float*)carve(CC * sizeof(float));
  (void)ws_size; (void)n_in; (void)out_size;

  hipMemsetAsync(deg, 0, (size_t)N * 4, stream);
  detect<<<1, 256, 0, stream>>>((const unsigned int*)e, (const unsigned int*)x, flags);
  count_deg<<<FB, 256, 0, stream>>>(e, E, N, flags, deg);
  scan_phase1<<<NB + 1, 256, 0, stream>>>(deg, N, bsums, NB,
                                          W1l, W1r, b1, W2l, W2r, b2,
                                          flags, Wp1f, Wc2f, b1f, b2f);
  scan_phase2<<<1, 1024, 0, stream>>>(bsums, NB, row_ptr, N);
  scan_phase3<<<NB, 256, 0, stream>>>(deg, N, bsums, row_ptr, fill, invd);
  fill_or_t1<<<hybrid_grid, 256, 0, stream>>>(e, E, N, flags, fill, col,
                                              x, Wp1f, b1f, t1, s1, T1B, FB);
  aggregate1<<<(N + 3) / 4, 256, 0, stream>>>(t1, s1, row_ptr, invd, col, h, N);
  agg2<<<(N + 3) / 4, 256, 0, stream>>>(h, row_ptr, invd, col, aggh, N);
  final_k<<<(N + 31) / 32, 256, 0, stream>>>(aggh, h, Wc2f, b2f, out, N);
}